// Round 15
// baseline (661.657 us; speedup 1.0000x reference)
//
#include <hip/hip_runtime.h>
#include <hip/hip_fp16.h>

#define NN 20000      // nodes
#define NE 320000     // edges
#define SS 2          // feature axis
#define FIN 128
#define FH 246

typedef _Float16 f16x8 __attribute__((ext_vector_type(8)));
typedef float f32x4 __attribute__((ext_vector_type(4)));

// ---------------- degree histogram ----------------
__global__ void degree_kernel(const int* __restrict__ src, const int* __restrict__ dst,
                              int* __restrict__ deg_out, int* __restrict__ deg_in) {
    int e = blockIdx.x * blockDim.x + threadIdx.x;
    if (e < NE) {
        atomicAdd(&deg_out[src[e]], 1);
        atomicAdd(&deg_in[dst[e]], 1);
    }
}

// ---------------- norms + parallel CSR range allocation (fused) ----------------
__global__ void alloc_kernel(const int* __restrict__ deg_out, const int* __restrict__ deg_in,
                             float* __restrict__ norm_out, float* __restrict__ norm_in,
                             int* __restrict__ row_start, int* __restrict__ cursor,
                             int* __restrict__ counter) {
    __shared__ int smem[256];
    __shared__ int base_s;
    int tid = threadIdx.x;
    int i = blockIdx.x * 256 + tid;
    int v = (i < NN) ? deg_in[i] : 0;
    smem[tid] = v;
    __syncthreads();
    for (int off = 1; off < 256; off <<= 1) {
        int t = (tid >= off) ? smem[tid - off] : 0;
        __syncthreads();
        smem[tid] += t;
        __syncthreads();
    }
    int incl = smem[tid];
    if (tid == 0) base_s = atomicAdd(counter, smem[255]);
    __syncthreads();
    if (i < NN) {
        int excl = base_s + incl - v;
        row_start[i] = excl;
        cursor[i]    = excl;
        norm_out[i] = rsqrtf(fmaxf((float)deg_out[i], 1.0f));
        norm_in[i]  = rsqrtf(fmaxf((float)v, 1.0f));
    }
}

// ---------------- scatter edges into CSR ----------------
__global__ void scatter_kernel(const int* __restrict__ src, const int* __restrict__ dst,
                               int* __restrict__ cursor, int* __restrict__ sorted_src) {
    int e = blockIdx.x * blockDim.x + threadIdx.x;
    if (e < NE) {
        int d = dst[e];
        int pos = atomicAdd(&cursor[d], 1);
        sorted_src[pos] = src[e];
    }
}

// ---------------- W pre-split (all 3 layers in one launch) ----------------
// Wt_hi/lo[n][k] = split_f16(W[k][n]), zero-padded 256x256; blockIdx.y = layer
__global__ void convert_w_all(const float* __restrict__ W0, const float* __restrict__ W1,
                              const float* __restrict__ W2,
                              ushort* __restrict__ Wh0, ushort* __restrict__ Wl0,
                              ushort* __restrict__ Wh1, ushort* __restrict__ Wl1,
                              ushort* __restrict__ Wh2, ushort* __restrict__ Wl2) {
    int n = blockIdx.x, k = threadIdx.x;
    const float* W; ushort* Wh; ushort* Wl; int K;
    if (blockIdx.y == 0)      { W = W0; Wh = Wh0; Wl = Wl0; K = FIN; }
    else if (blockIdx.y == 1) { W = W1; Wh = Wh1; Wl = Wl1; K = FH; }
    else                      { W = W2; Wh = Wh2; Wl = Wl2; K = FH; }
    float v = (k < K && n < 246) ? W[k * 246 + n] : 0.f;
    _Float16 h = (_Float16)v;
    _Float16 l = (_Float16)(v - (float)h);
    Wh[n * 256 + k] = *(ushort*)&h;
    Wl[n * 256 + k] = *(ushort*)&l;
}

__global__ void init_out(float* __restrict__ out, const float* __restrict__ fcb) {
    int i = blockIdx.x * 256 + threadIdx.x;
    if (i < NN) out[i] = fcb[0];
}

// ---------------- chunk-tiled gather-aggregate, split-f16 output (round-14) ----------
template<int F4ROW>
__global__ void aggregate2(const float* __restrict__ h,
                           const int* __restrict__ row_start,
                           const int* __restrict__ deg_in,
                           const int* __restrict__ sorted_src,
                           const float* __restrict__ norm_out,
                           const float* __restrict__ norm_in,
                           ushort* __restrict__ Ah, ushort* __restrict__ Al) {
    int g  = threadIdx.x >> 5;              // 0..3: node sub-index
    int l  = threadIdx.x & 31;
    int n  = blockIdx.x * 4 + g;
    if (n >= NN) return;
    int idx = blockIdx.y * 32 + l;          // < F4ROW (F4ROW multiple of 32)
    const float4* hv = (const float4*)h;
    int beg = row_start[n];
    int end = beg + deg_in[n];
    float4 acc = {0.f, 0.f, 0.f, 0.f};
    int i = beg;
    for (; i + 4 <= end; i += 4) {
        int s0 = sorted_src[i + 0];
        int s1 = sorted_src[i + 1];
        int s2 = sorted_src[i + 2];
        int s3 = sorted_src[i + 3];
        float n0 = norm_out[s0], n1 = norm_out[s1];
        float n2 = norm_out[s2], n3 = norm_out[s3];
        float4 v0 = hv[(size_t)s0 * F4ROW + idx];
        float4 v1 = hv[(size_t)s1 * F4ROW + idx];
        float4 v2 = hv[(size_t)s2 * F4ROW + idx];
        float4 v3 = hv[(size_t)s3 * F4ROW + idx];
        acc.x += v0.x * n0 + v1.x * n1 + v2.x * n2 + v3.x * n3;
        acc.y += v0.y * n0 + v1.y * n1 + v2.y * n2 + v3.y * n3;
        acc.z += v0.z * n0 + v1.z * n1 + v2.z * n2 + v3.z * n3;
        acc.w += v0.w * n0 + v1.w * n1 + v2.w * n2 + v3.w * n3;
    }
    for (; i < end; ++i) {
        int s = sorted_src[i];
        float nr = norm_out[s];
        float4 v = hv[(size_t)s * F4ROW + idx];
        acc.x += v.x * nr;
        acc.y += v.y * nr;
        acc.z += v.z * nr;
        acc.w += v.w * nr;
    }
    float ni = norm_in[n];
    float v[4] = {acc.x * ni, acc.y * ni, acc.z * ni, acc.w * ni};
    ushort hp[4], lp[4];
#pragma unroll
    for (int j = 0; j < 4; ++j) {
        _Float16 hh = (_Float16)v[j];
        _Float16 ll = (_Float16)(v[j] - (float)hh);
        hp[j] = *(ushort*)&hh;
        lp[j] = *(ushort*)&ll;
    }
    ((uint2*)Ah)[(size_t)n * F4ROW + idx] = *(uint2*)hp;
    ((uint2*)Al)[(size_t)n * F4ROW + idx] = *(uint2*)lp;
}

// ---------------- persistent-B split-f16 MFMA GEMM (barrier-free K-loop) ----------
// D[m,c] = relu( A[m,:] . W[:,c] + b[c] ), A = pre-split f16 hi/lo [40000][KP]
// (k-pads zero, norm_in folded), W pre-split f16 hi/lo [256][256] (k-pads zero).
// Block = 512 threads (8 waves, 2/SIMD), grid (128, 2) = 256 blocks = 1/CU.
// Each block stages its 128-col B-half at FULL K into LDS once (<=135 KB), one
// __syncthreads, then each wave independently grid-strides over 32-row m-tiles:
// per k-tile 4 direct-global A uint4 (double-buffered) + 16 ds_read_b128 +
// 48 MFMA, ZERO barriers. Per-acc MFMA order (hh,lh,hl over same t0 sequence)
// identical to round 14 -> bitwise-same numerics (absmax 4.9e-4).
// FUSE: relu -> *fc_w -> mean_s -> 16-lane reduce -> atomicAdd(out[node], 0.5p).
template<int KP, bool FUSE>
__global__ __launch_bounds__(512) void gemm_persist(const ushort* __restrict__ Ah,
                                                    const ushort* __restrict__ Al,
                                                    const ushort* __restrict__ Wh,
                                                    const ushort* __restrict__ Wl,
                                                    const float* __restrict__ b,
                                                    void* __restrict__ outv,
                                                    const float* __restrict__ fcw) {
    constexpr int NT = KP / 32;            // k-tiles (4 | 8)
    constexpr int R4 = KP / 8;             // uint4 per A row / per B row-slice
    __shared__ __align__(16) _Float16 Bh_s[128][KP + 8];
    __shared__ __align__(16) _Float16 Bl_s[128][KP + 8];

    int tid  = threadIdx.x;
    int n0   = blockIdx.y * 128;
    int wave = tid >> 6, lane = tid & 63;
    int lr = lane & 15, quad = lane >> 4;

    // ---- stage B once: 128 rows x KP, hi+lo
    const uint4* Whv = (const uint4*)Wh;   // padded row stride 32 uint4
    const uint4* Wlv = (const uint4*)Wl;
#pragma unroll
    for (int it = 0; it < (128 * R4) / 512; ++it) {
        int f  = it * 512 + tid;
        int rn = f / R4, q = f % R4;
        size_t base = (size_t)(n0 + rn) * 32 + q;
        *(uint4*)&Bh_s[rn][q * 8] = Whv[base];
        *(uint4*)&Bl_s[rn][q * 8] = Wlv[base];
    }
    __syncthreads();

    const uint4* Ahv = (const uint4*)Ah;
    const uint4* Alv = (const uint4*)Al;

    for (int t = blockIdx.x * 8 + wave; t < (NN * SS) / 32; t += 128 * 8) {
        int tb = t * 32;                   // m-tile base row
        f32x4 acc[2][8];
#pragma unroll
        for (int mi = 0; mi < 2; ++mi)
#pragma unroll
            for (int ni = 0; ni < 8; ++ni) acc[mi][ni] = {0.f, 0.f, 0.f, 0.f};

        size_t arow[2];
#pragma unroll
        for (int mi = 0; mi < 2; ++mi)
            arow[mi] = (size_t)(tb + mi * 16 + lr) * R4 + quad;

        uint4 cah[2], cal[2];
#pragma unroll
        for (int mi = 0; mi < 2; ++mi) {
            cah[mi] = Ahv[arow[mi]];
            cal[mi] = Alv[arow[mi]];
        }
        for (int t0 = 0; t0 < NT; ++t0) {
            uint4 nah[2], nal[2];
            if (t0 + 1 < NT) {
#pragma unroll
                for (int mi = 0; mi < 2; ++mi) {
                    nah[mi] = Ahv[arow[mi] + (t0 + 1) * 4];
                    nal[mi] = Alv[arow[mi] + (t0 + 1) * 4];
                }
            }
            f16x8 ahf[2], alf[2];
#pragma unroll
            for (int mi = 0; mi < 2; ++mi) {
                ahf[mi] = *(f16x8*)&cah[mi];
                alf[mi] = *(f16x8*)&cal[mi];
            }
            int ko = t0 * 32 + quad * 8;
#pragma unroll
            for (int ni = 0; ni < 8; ++ni) {
                f16x8 bh = *(const f16x8*)&Bh_s[ni * 16 + lr][ko];
                f16x8 bl = *(const f16x8*)&Bl_s[ni * 16 + lr][ko];
                acc[0][ni] = __builtin_amdgcn_mfma_f32_16x16x32_f16(ahf[0], bh, acc[0][ni], 0, 0, 0);
                acc[1][ni] = __builtin_amdgcn_mfma_f32_16x16x32_f16(ahf[1], bh, acc[1][ni], 0, 0, 0);
                acc[0][ni] = __builtin_amdgcn_mfma_f32_16x16x32_f16(alf[0], bh, acc[0][ni], 0, 0, 0);
                acc[1][ni] = __builtin_amdgcn_mfma_f32_16x16x32_f16(alf[1], bh, acc[1][ni], 0, 0, 0);
                acc[0][ni] = __builtin_amdgcn_mfma_f32_16x16x32_f16(ahf[0], bl, acc[0][ni], 0, 0, 0);
                acc[1][ni] = __builtin_amdgcn_mfma_f32_16x16x32_f16(ahf[1], bl, acc[1][ni], 0, 0, 0);
            }
#pragma unroll
            for (int mi = 0; mi < 2; ++mi) { cah[mi] = nah[mi]; cal[mi] = nal[mi]; }
        }

        if (FUSE) {
            float* out = (float*)outv;
#pragma unroll
            for (int mi = 0; mi < 2; ++mi) {
#pragma unroll
                for (int i = 0; i < 4; ++i) {
                    float p = 0.f;
#pragma unroll
                    for (int ni = 0; ni < 8; ++ni) {
                        int c = n0 + ni * 16 + lr;
                        if (c < 246)
                            p += fmaxf(acc[mi][ni][i] + b[c], 0.f) * fcw[c];
                    }
#pragma unroll
                    for (int off = 8; off > 0; off >>= 1)
                        p += __shfl_down(p, off, 16);
                    if (lr == 0) {
                        int m = tb + mi * 16 + quad * 4 + i;
                        atomicAdd(&out[m >> 1], 0.5f * p);
                    }
                }
            }
        } else {
            float* outF = (float*)outv;    // fp32 [M][256]; pad cols get 0 naturally
#pragma unroll
            for (int ni = 0; ni < 8; ++ni) {
                int c = n0 + ni * 16 + lr;
                float bj = (c < 246) ? b[c] : 0.f;
#pragma unroll
                for (int mi = 0; mi < 2; ++mi)
#pragma unroll
                    for (int i = 0; i < 4; ++i) {
                        int m = tb + mi * 16 + quad * 4 + i;
                        outF[(size_t)m * 256 + c] = fmaxf(acc[mi][ni][i] + bj, 0.f);
                    }
            }
        }
    }
}

extern "C" void kernel_launch(void* const* d_in, const int* in_sizes, int n_in,
                              void* d_out, int out_size, void* d_ws, size_t ws_size,
                              hipStream_t stream) {
    const float* feat = (const float*)d_in[0];
    const int*   src  = (const int*)d_in[1];
    const int*   dst  = (const int*)d_in[2];
    const float* W0   = (const float*)d_in[3];
    const float* b0   = (const float*)d_in[4];
    const float* W1   = (const float*)d_in[5];
    const float* b1   = (const float*)d_in[6];
    const float* W2   = (const float*)d_in[7];
    const float* b2   = (const float*)d_in[8];
    const float* fcw  = (const float*)d_in[9];
    const float* fcb  = (const float*)d_in[10];
    float* out = (float*)d_out;

    char* ws = (char*)d_ws;
    size_t off = 0;
    auto alloc = [&](size_t bytes) {
        void* p = ws + off;
        off = (off + bytes + 255) & ~(size_t)255;
        return p;
    };
    int*    deg_out_i = (int*)alloc((2 * NN + 64) * sizeof(int));
    int*    deg_in_i  = deg_out_i + NN;
    int*    counter   = deg_out_i + 2 * NN;
    int*    row_start = (int*)alloc(NN * sizeof(int));
    int*    cursor    = (int*)alloc(NN * sizeof(int));
    int*    sorted    = (int*)alloc(NE * sizeof(int));
    float*  norm_out  = (float*)alloc(NN * sizeof(float));
    float*  norm_in   = (float*)alloc(NN * sizeof(float));
    ushort* Wh0 = (ushort*)alloc(256 * 256 * sizeof(ushort));
    ushort* Wl0 = (ushort*)alloc(256 * 256 * sizeof(ushort));
    ushort* Wh1 = (ushort*)alloc(256 * 256 * sizeof(ushort));
    ushort* Wl1 = (ushort*)alloc(256 * 256 * sizeof(ushort));
    ushort* Wh2 = (ushort*)alloc(256 * 256 * sizeof(ushort));
    ushort* Wl2 = (ushort*)alloc(256 * 256 * sizeof(ushort));
    ushort* Ahb = (ushort*)alloc((size_t)NN * SS * 256 * sizeof(ushort));  // split A hi
    ushort* Alb = (ushort*)alloc((size_t)NN * SS * 256 * sizeof(ushort));  // split A lo
    float*  bufH = (float*)alloc((size_t)NN * SS * 256 * sizeof(float));   // gemm out (padded)

    hipMemsetAsync(deg_out_i, 0, (2 * NN + 1) * sizeof(int), stream);

    degree_kernel<<<(NE + 255) / 256, 256, 0, stream>>>(src, dst, deg_out_i, deg_in_i);
    alloc_kernel<<<(NN + 255) / 256, 256, 0, stream>>>(deg_out_i, deg_in_i, norm_out, norm_in,
                                                       row_start, cursor, counter);
    scatter_kernel<<<(NE + 255) / 256, 256, 0, stream>>>(src, dst, cursor, sorted);

    convert_w_all<<<dim3(256, 3), 256, 0, stream>>>(W0, W1, W2, Wh0, Wl0, Wh1, Wl1, Wh2, Wl2);
    init_out<<<(NN + 255) / 256, 256, 0, stream>>>(out, fcb);

    const int NB = (NN + 3) / 4;     // 5000
    dim3 pgrid(128, 2);              // 256 persistent blocks (1 per CU)

    // Layer 0: feat [N][2*128] -> agg+split (Ah/Al, row 128) -> gemm -> h1(bufH, 256)
    aggregate2<64><<<dim3(NB, 2), 128, 0, stream>>>(feat, row_start, deg_in_i, sorted,
                                                    norm_out, norm_in, Ahb, Alb);
    gemm_persist<FIN, false><<<pgrid, 512, 0, stream>>>(Ahb, Alb, Wh0, Wl0, b0, bufH, fcw);

    // Layer 1: h1 -> agg+split (row 256) -> gemm -> h2(bufH)
    aggregate2<128><<<dim3(NB, 4), 128, 0, stream>>>(bufH, row_start, deg_in_i, sorted,
                                                     norm_out, norm_in, Ahb, Alb);
    gemm_persist<256, false><<<pgrid, 512, 0, stream>>>(Ahb, Alb, Wh1, Wl1, b1, bufH, fcw);

    // Layer 2: h2 -> agg+split -> fused gemm -> out (atomicAdd; out pre-set to fcb)
    aggregate2<128><<<dim3(NB, 4), 128, 0, stream>>>(bufH, row_start, deg_in_i, sorted,
                                                     norm_out, norm_in, Ahb, Alb);
    gemm_persist<256, true><<<pgrid, 512, 0, stream>>>(Ahb, Alb, Wh2, Wl2, b2, out, fcw);
}

// Round 16
// 370.242 us; speedup vs baseline: 1.7871x; 1.7871x over previous
//
#include <hip/hip_runtime.h>
#include <hip/hip_fp16.h>

#define NN 20000      // nodes
#define NE 320000     // edges
#define SS 2          // feature axis
#define FIN 128
#define FH 246

typedef _Float16 f16x8 __attribute__((ext_vector_type(8)));
typedef float f32x4 __attribute__((ext_vector_type(4)));

// ---------------- degree histogram ----------------
__global__ void degree_kernel(const int* __restrict__ src, const int* __restrict__ dst,
                              int* __restrict__ deg_out, int* __restrict__ deg_in) {
    int e = blockIdx.x * blockDim.x + threadIdx.x;
    if (e < NE) {
        atomicAdd(&deg_out[src[e]], 1);
        atomicAdd(&deg_in[dst[e]], 1);
    }
}

// ---------------- norms + parallel CSR range allocation (fused) ----------------
__global__ void alloc_kernel(const int* __restrict__ deg_out, const int* __restrict__ deg_in,
                             float* __restrict__ norm_out, float* __restrict__ norm_in,
                             int* __restrict__ row_start, int* __restrict__ cursor,
                             int* __restrict__ counter) {
    __shared__ int smem[256];
    __shared__ int base_s;
    int tid = threadIdx.x;
    int i = blockIdx.x * 256 + tid;
    int v = (i < NN) ? deg_in[i] : 0;
    smem[tid] = v;
    __syncthreads();
    for (int off = 1; off < 256; off <<= 1) {
        int t = (tid >= off) ? smem[tid - off] : 0;
        __syncthreads();
        smem[tid] += t;
        __syncthreads();
    }
    int incl = smem[tid];
    if (tid == 0) base_s = atomicAdd(counter, smem[255]);
    __syncthreads();
    if (i < NN) {
        int excl = base_s + incl - v;
        row_start[i] = excl;
        cursor[i]    = excl;
        norm_out[i] = rsqrtf(fmaxf((float)deg_out[i], 1.0f));
        norm_in[i]  = rsqrtf(fmaxf((float)v, 1.0f));
    }
}

// ---------------- scatter edges into CSR ----------------
__global__ void scatter_kernel(const int* __restrict__ src, const int* __restrict__ dst,
                               int* __restrict__ cursor, int* __restrict__ sorted_src) {
    int e = blockIdx.x * blockDim.x + threadIdx.x;
    if (e < NE) {
        int d = dst[e];
        int pos = atomicAdd(&cursor[d], 1);
        sorted_src[pos] = src[e];
    }
}

// ---------------- W pre-split (all 3 layers in one launch) ----------------
__global__ void convert_w_all(const float* __restrict__ W0, const float* __restrict__ W1,
                              const float* __restrict__ W2,
                              ushort* __restrict__ Wh0, ushort* __restrict__ Wl0,
                              ushort* __restrict__ Wh1, ushort* __restrict__ Wl1,
                              ushort* __restrict__ Wh2, ushort* __restrict__ Wl2) {
    int n = blockIdx.x, k = threadIdx.x;
    const float* W; ushort* Wh; ushort* Wl; int K;
    if (blockIdx.y == 0)      { W = W0; Wh = Wh0; Wl = Wl0; K = FIN; }
    else if (blockIdx.y == 1) { W = W1; Wh = Wh1; Wl = Wl1; K = FH; }
    else                      { W = W2; Wh = Wh2; Wl = Wl2; K = FH; }
    float v = (k < K && n < 246) ? W[k * 246 + n] : 0.f;
    _Float16 h = (_Float16)v;
    _Float16 l = (_Float16)(v - (float)h);
    Wh[n * 256 + k] = *(ushort*)&h;
    Wl[n * 256 + k] = *(ushort*)&l;
}

__global__ void init_out(float* __restrict__ out, const float* __restrict__ fcb) {
    int i = blockIdx.x * 256 + threadIdx.x;
    if (i < NN) out[i] = fcb[0];
}

// ---------------- XCD-pinned chunk-tiled gather-aggregate, split-f16 output ----------
// agg[n,:] = norm_in[n] * sum_{e: dst=n} h[src,:]*norm_out[src], output split to
// f16 hi/lo (Ah, Al) -- identical numerics to round 14 (absmax 4.9e-4).
// XCD PINNING: chunk = blockIdx.x % NCH (NCH = 8 for H, 4 for L0; 256 B chunks).
// With round-robin block->XCD dispatch, each XCD only gathers from ONE 1/NCH
// column slice (~5.1 MB, ~L2-resident) instead of streaming the whole 41 MB
// buffer through its L2 (8x compulsory-traffic cut). Wrong dispatch mapping ->
// perf no-op, never a correctness issue. Summation order per (n,idx) unchanged.
// 128 threads = 8 nodes x 16 lanes; lane owns float4 #(chunk*16+l).
template<int F4ROW, int NCH>
__global__ void aggregate2(const float* __restrict__ h,
                           const int* __restrict__ row_start,
                           const int* __restrict__ deg_in,
                           const int* __restrict__ sorted_src,
                           const float* __restrict__ norm_out,
                           const float* __restrict__ norm_in,
                           ushort* __restrict__ Ah, ushort* __restrict__ Al) {
    int g  = threadIdx.x >> 4;              // 0..7: node sub-index
    int l  = threadIdx.x & 15;              // float4 within chunk
    int cb = blockIdx.x & (NCH - 1);        // chunk (XCD-pinned axis)
    int nb = blockIdx.x / NCH;              // node group
    int n  = nb * 8 + g;
    if (n >= NN) return;
    int idx = cb * 16 + l;                  // < F4ROW (= NCH*16)
    const float4* hv = (const float4*)h;
    int beg = row_start[n];
    int end = beg + deg_in[n];
    float4 acc = {0.f, 0.f, 0.f, 0.f};
    int i = beg;
    for (; i + 4 <= end; i += 4) {
        int s0 = sorted_src[i + 0];
        int s1 = sorted_src[i + 1];
        int s2 = sorted_src[i + 2];
        int s3 = sorted_src[i + 3];
        float n0 = norm_out[s0], n1 = norm_out[s1];
        float n2 = norm_out[s2], n3 = norm_out[s3];
        float4 v0 = hv[(size_t)s0 * F4ROW + idx];
        float4 v1 = hv[(size_t)s1 * F4ROW + idx];
        float4 v2 = hv[(size_t)s2 * F4ROW + idx];
        float4 v3 = hv[(size_t)s3 * F4ROW + idx];
        acc.x += v0.x * n0 + v1.x * n1 + v2.x * n2 + v3.x * n3;
        acc.y += v0.y * n0 + v1.y * n1 + v2.y * n2 + v3.y * n3;
        acc.z += v0.z * n0 + v1.z * n1 + v2.z * n2 + v3.z * n3;
        acc.w += v0.w * n0 + v1.w * n1 + v2.w * n2 + v3.w * n3;
    }
    for (; i < end; ++i) {
        int s = sorted_src[i];
        float nr = norm_out[s];
        float4 v = hv[(size_t)s * F4ROW + idx];
        acc.x += v.x * nr;
        acc.y += v.y * nr;
        acc.z += v.z * nr;
        acc.w += v.w * nr;
    }
    float ni = norm_in[n];
    float v[4] = {acc.x * ni, acc.y * ni, acc.z * ni, acc.w * ni};
    ushort hp[4], lp[4];
#pragma unroll
    for (int j = 0; j < 4; ++j) {
        _Float16 hh = (_Float16)v[j];
        _Float16 ll = (_Float16)(v[j] - (float)hh);
        hp[j] = *(ushort*)&hh;
        lp[j] = *(ushort*)&ll;
    }
    ((uint2*)Ah)[(size_t)n * F4ROW + idx] = *(uint2*)hp;
    ((uint2*)Al)[(size_t)n * F4ROW + idx] = *(uint2*)lp;
}

// ---------------- split-f16 MFMA GEMM, pre-split A (round-14, known-good) ----------
// D[m,c] = relu( A[m,:] . W[:,c] + b[c] ), A = pre-split f16 hi/lo [40000][KP]
// (KP=128|256, k-pads zero, norm_in folded), W pre-split f16 hi/lo [256][256].
// Block 64M x 128N, 4 waves 2x2, wave tile 32x64 via 2x4 mfma_f32_16x16x32_f16;
// acc += Ah*Wh + Al*Wh + Ah*Wl. Grid (625, 2). No VALU in the K-loop.
// FUSE: relu -> *fc_w -> mean_s -> 16-lane reduce -> atomicAdd(out[node], 0.5p).
template<int KP, bool FUSE>
__global__ __launch_bounds__(256) void gemm_split(const ushort* __restrict__ Ah,
                                                  const ushort* __restrict__ Al,
                                                  const ushort* __restrict__ Wh,
                                                  const ushort* __restrict__ Wl,
                                                  const float* __restrict__ b,
                                                  void* __restrict__ outv,
                                                  const float* __restrict__ fcw) {
    constexpr int NT = KP / 32;
    constexpr int AS = KP / 8;             // A row stride in uint4
    __shared__ __align__(16) _Float16 Ah_s[64][40];
    __shared__ __align__(16) _Float16 Al_s[64][40];
    __shared__ __align__(16) _Float16 Bh_s[128][40];
    __shared__ __align__(16) _Float16 Bl_s[128][40];

    int tid  = threadIdx.x;
    int m0   = blockIdx.x * 64;
    int n0   = blockIdx.y * 128;
    int wave = tid >> 6, lane = tid & 63;
    int wm = wave >> 1, wn = wave & 1;
    int lr = lane & 15, quad = lane >> 4;

    f32x4 acc[2][4];
#pragma unroll
    for (int mi = 0; mi < 2; ++mi)
#pragma unroll
        for (int ni = 0; ni < 4; ++ni) acc[mi][ni] = {0.f, 0.f, 0.f, 0.f};

    int ar = tid >> 2;                 // A row 0..63
    int aq = tid & 3;                  // uint4 within 64B k-tile
    const uint4* Ahv = (const uint4*)Ah;
    const uint4* Alv = (const uint4*)Al;
    const uint4* Whv = (const uint4*)Wh;   // row stride 32 uint4
    const uint4* Wlv = (const uint4*)Wl;

    for (int t0 = 0; t0 < NT; ++t0) {
        // ---- stage A: 64 rows x 32 k, hi+lo (1 uint4/thread each), pure copy
        size_t abase = (size_t)(m0 + ar) * AS + t0 * 4 + aq;
        *(uint4*)&Ah_s[ar][aq * 8] = Ahv[abase];
        *(uint4*)&Al_s[ar][aq * 8] = Alv[abase];
        // ---- stage B: 128 rows x 32 k, hi+lo (2 uint4/thread each)
#pragma unroll
        for (int it = 0; it < 2; ++it) {
            int f = it * 256 + tid;
            int rn = f >> 2, q = f & 3;
            size_t base = (size_t)(n0 + rn) * 32 + t0 * 4 + q;
            *(uint4*)&Bh_s[rn][q * 8] = Whv[base];
            *(uint4*)&Bl_s[rn][q * 8] = Wlv[base];
        }
        __syncthreads();

        f16x8 ah[2], al[2], bh[4], bl[4];
#pragma unroll
        for (int mi = 0; mi < 2; ++mi) {
            ah[mi] = *(const f16x8*)&Ah_s[wm * 32 + mi * 16 + lr][quad * 8];
            al[mi] = *(const f16x8*)&Al_s[wm * 32 + mi * 16 + lr][quad * 8];
        }
#pragma unroll
        for (int ni = 0; ni < 4; ++ni) {
            bh[ni] = *(const f16x8*)&Bh_s[wn * 64 + ni * 16 + lr][quad * 8];
            bl[ni] = *(const f16x8*)&Bl_s[wn * 64 + ni * 16 + lr][quad * 8];
        }
#pragma unroll
        for (int mi = 0; mi < 2; ++mi)
#pragma unroll
            for (int ni = 0; ni < 4; ++ni) {
                acc[mi][ni] = __builtin_amdgcn_mfma_f32_16x16x32_f16(ah[mi], bh[ni], acc[mi][ni], 0, 0, 0);
                acc[mi][ni] = __builtin_amdgcn_mfma_f32_16x16x32_f16(al[mi], bh[ni], acc[mi][ni], 0, 0, 0);
                acc[mi][ni] = __builtin_amdgcn_mfma_f32_16x16x32_f16(ah[mi], bl[ni], acc[mi][ni], 0, 0, 0);
            }
        __syncthreads();
    }

    if (FUSE) {
        float* out = (float*)outv;
#pragma unroll
        for (int mi = 0; mi < 2; ++mi) {
#pragma unroll
            for (int i = 0; i < 4; ++i) {
                float p = 0.f;
#pragma unroll
                for (int ni = 0; ni < 4; ++ni) {
                    int c = n0 + wn * 64 + ni * 16 + lr;
                    if (c < 246)
                        p += fmaxf(acc[mi][ni][i] + b[c], 0.f) * fcw[c];
                }
#pragma unroll
                for (int off = 8; off > 0; off >>= 1)
                    p += __shfl_down(p, off, 16);
                if (lr == 0) {
                    int m = m0 + wm * 32 + mi * 16 + quad * 4 + i;
                    atomicAdd(&out[m >> 1], 0.5f * p);
                }
            }
        }
    } else {
        float* outF = (float*)outv;    // fp32 [M][256]; cols>=246 get 0 (acc=0, bj=0)
#pragma unroll
        for (int ni = 0; ni < 4; ++ni) {
            int c = n0 + wn * 64 + ni * 16 + lr;
            float bj = (c < 246) ? b[c] : 0.f;
#pragma unroll
            for (int mi = 0; mi < 2; ++mi)
#pragma unroll
                for (int i = 0; i < 4; ++i) {
                    int m = m0 + wm * 32 + mi * 16 + quad * 4 + i;
                    outF[(size_t)m * 256 + c] = fmaxf(acc[mi][ni][i] + bj, 0.f);
                }
        }
    }
}

extern "C" void kernel_launch(void* const* d_in, const int* in_sizes, int n_in,
                              void* d_out, int out_size, void* d_ws, size_t ws_size,
                              hipStream_t stream) {
    const float* feat = (const float*)d_in[0];
    const int*   src  = (const int*)d_in[1];
    const int*   dst  = (const int*)d_in[2];
    const float* W0   = (const float*)d_in[3];
    const float* b0   = (const float*)d_in[4];
    const float* W1   = (const float*)d_in[5];
    const float* b1   = (const float*)d_in[6];
    const float* W2   = (const float*)d_in[7];
    const float* b2   = (const float*)d_in[8];
    const float* fcw  = (const float*)d_in[9];
    const float* fcb  = (const float*)d_in[10];
    float* out = (float*)d_out;

    char* ws = (char*)d_ws;
    size_t off = 0;
    auto alloc = [&](size_t bytes) {
        void* p = ws + off;
        off = (off + bytes + 255) & ~(size_t)255;
        return p;
    };
    int*    deg_out_i = (int*)alloc((2 * NN + 64) * sizeof(int));
    int*    deg_in_i  = deg_out_i + NN;
    int*    counter   = deg_out_i + 2 * NN;
    int*    row_start = (int*)alloc(NN * sizeof(int));
    int*    cursor    = (int*)alloc(NN * sizeof(int));
    int*    sorted    = (int*)alloc(NE * sizeof(int));
    float*  norm_out  = (float*)alloc(NN * sizeof(float));
    float*  norm_in   = (float*)alloc(NN * sizeof(float));
    ushort* Wh0 = (ushort*)alloc(256 * 256 * sizeof(ushort));
    ushort* Wl0 = (ushort*)alloc(256 * 256 * sizeof(ushort));
    ushort* Wh1 = (ushort*)alloc(256 * 256 * sizeof(ushort));
    ushort* Wl1 = (ushort*)alloc(256 * 256 * sizeof(ushort));
    ushort* Wh2 = (ushort*)alloc(256 * 256 * sizeof(ushort));
    ushort* Wl2 = (ushort*)alloc(256 * 256 * sizeof(ushort));
    ushort* Ahb = (ushort*)alloc((size_t)NN * SS * 256 * sizeof(ushort));  // split A hi
    ushort* Alb = (ushort*)alloc((size_t)NN * SS * 256 * sizeof(ushort));  // split A lo
    float*  bufH = (float*)alloc((size_t)NN * SS * 256 * sizeof(float));   // gemm out (padded)

    hipMemsetAsync(deg_out_i, 0, (2 * NN + 1) * sizeof(int), stream);

    degree_kernel<<<(NE + 255) / 256, 256, 0, stream>>>(src, dst, deg_out_i, deg_in_i);
    alloc_kernel<<<(NN + 255) / 256, 256, 0, stream>>>(deg_out_i, deg_in_i, norm_out, norm_in,
                                                       row_start, cursor, counter);
    scatter_kernel<<<(NE + 255) / 256, 256, 0, stream>>>(src, dst, cursor, sorted);

    convert_w_all<<<dim3(256, 3), 256, 0, stream>>>(W0, W1, W2, Wh0, Wl0, Wh1, Wl1, Wh2, Wl2);
    init_out<<<(NN + 255) / 256, 256, 0, stream>>>(out, fcb);

    const int NB8 = (NN + 7) / 8;    // 2500 node groups (8 nodes/block)
    dim3 ggrid(NN * SS / 64, 2);     // 625 x 2

    // Layer 0: feat [N][2*128] -> agg+split (chunk = blk%4) -> gemm -> h1(bufH, 256)
    aggregate2<64, 4><<<NB8 * 4, 128, 0, stream>>>(feat, row_start, deg_in_i, sorted,
                                                   norm_out, norm_in, Ahb, Alb);
    gemm_split<FIN, false><<<ggrid, 256, 0, stream>>>(Ahb, Alb, Wh0, Wl0, b0, bufH, fcw);

    // Layer 1: h1 -> agg+split (chunk = blk%8) -> gemm -> h2(bufH)
    aggregate2<128, 8><<<NB8 * 8, 128, 0, stream>>>(bufH, row_start, deg_in_i, sorted,
                                                    norm_out, norm_in, Ahb, Alb);
    gemm_split<256, false><<<ggrid, 256, 0, stream>>>(Ahb, Alb, Wh1, Wl1, b1, bufH, fcw);

    // Layer 2: h2 -> agg+split -> fused gemm -> out (atomicAdd; out pre-set to fcb)
    aggregate2<128, 8><<<NB8 * 8, 128, 0, stream>>>(bufH, row_start, deg_in_i, sorted,
                                                    norm_out, norm_in, Ahb, Alb);
    gemm_split<256, true><<<ggrid, 256, 0, stream>>>(Ahb, Alb, Wh2, Wl2, b2, out, fcw);
}